// Round 16
// baseline (460.209 us; speedup 1.0000x reference)
//
#include <hip/hip_runtime.h>

#define EPSF 1e-7f
#define NBMAX 512   // max dst-buckets (ceil(N/128)); N=50000 -> 391

typedef __attribute__((ext_vector_type(4))) _Float16 half4;
typedef __attribute__((ext_vector_type(2))) _Float16 half2v;
typedef unsigned long long u64;

__device__ __forceinline__ float lrelu02(float x){ return x > 0.f ? x : 0.2f*x; }

// ---------------- CSR build (bucket-local, no N-sized scan) ----------------
__global__ __launch_bounds__(256) void k_bhist(
    const int* __restrict__ dst0, int E0, const int* __restrict__ dst1, int E1,
    int* __restrict__ bcnt0, int* __restrict__ bcnt1, int nb) {
  __shared__ int h0[NBMAX], h1[NBMAX];
  const int tid = threadIdx.x;
  const int g = blockIdx.x*blockDim.x + tid;
  const int stride = gridDim.x*blockDim.x;
  for (int i = tid; i < nb; i += 256) { h0[i] = 0; h1[i] = 0; }
  __syncthreads();
  for (int i = g; i < E0; i += stride) atomicAdd(&h0[dst0[i] >> 7], 1);
  for (int i = g; i < E1; i += stride) atomicAdd(&h1[dst1[i] >> 7], 1);
  __syncthreads();
  for (int i = tid; i < nb; i += 256) {
    if (h0[i]) atomicAdd(&bcnt0[i], h0[i]);
    if (h1[i]) atomicAdd(&bcnt1[i], h1[i]);
  }
}

__global__ __launch_bounds__(1024) void k_bscan(
    const int* __restrict__ bcnt0, int* __restrict__ bbase0, int* __restrict__ bcur0,
    const int* __restrict__ bcnt1, int* __restrict__ bbase1, int* __restrict__ bcur1,
    int nb) {
  __shared__ int wt[16];
  const int tid = threadIdx.x;
  const int half = tid >> 9, idx = tid & 511;
  const int* bcnt = half ? bcnt1 : bcnt0;
  int* bbase = half ? bbase1 : bbase0;
  int* bcur  = half ? bcur1  : bcur0;
  int v = (idx < nb) ? bcnt[idx] : 0;
  const int lane = tid & 63, w = tid >> 6;
  int inc = v;
  #pragma unroll
  for (int o = 1; o < 64; o <<= 1) { int t = __shfl_up(inc, o); if (lane >= o) inc += t; }
  if (lane == 63) wt[w] = inc;
  __syncthreads();
  int woff = 0;
  for (int i = half*8; i < w; ++i) woff += wt[i];
  int excl = woff + inc - v;
  if (idx < nb) { bbase[idx] = excl; bcur[idx] = excl; }
  if (idx == nb-1) bbase[nb] = excl + v;
}

__global__ __launch_bounds__(256) void k_bucketA(
    const int* __restrict__ src0, const int* __restrict__ dst0,
    int* __restrict__ bcur0, u64* __restrict__ temp0, int E0, int blocksA0,
    const int* __restrict__ src1, const int* __restrict__ dst1,
    int* __restrict__ bcur1, u64* __restrict__ temp1, int E1, int nb) {
  const int g0 = (blockIdx.x < blocksA0);
  const int* src = g0 ? src0 : src1;
  const int* dst = g0 ? dst0 : dst1;
  int* bcur      = g0 ? bcur0 : bcur1;
  u64* temp      = g0 ? temp0 : temp1;
  const int E    = g0 ? E0 : E1;
  const int cb   = g0 ? blockIdx.x : blockIdx.x - blocksA0;
  __shared__ int hist[NBMAX];
  __shared__ int lbase[NBMAX];
  const int tid = threadIdx.x;
  const int chunk0 = cb * 4096;
  const int e_end = min(chunk0 + 4096, E);
  for (int i = tid; i < nb; i += 256) hist[i] = 0;
  __syncthreads();
  for (int i = chunk0 + tid; i < e_end; i += 256)
    atomicAdd(&hist[dst[i] >> 7], 1);
  __syncthreads();
  for (int bn = tid; bn < nb; bn += 256) {
    int c = hist[bn];
    lbase[bn] = c ? atomicAdd(&bcur[bn], c) : 0;
    hist[bn] = 0;
  }
  __syncthreads();
  for (int i = chunk0 + tid; i < e_end; i += 256) {
    int d = dst[i];
    int bn = d >> 7;
    int off = atomicAdd(&hist[bn], 1);
    temp[(size_t)lbase[bn] + off] = ((u64)(unsigned)d << 32) | (unsigned)src[i];
  }
}

// pass B: per bucket, per-dst count + local scan -> rowptr; scatter csrc.
// For graph 0 additionally: per-edge attention weights (fp16) + per-dst denominators.
__global__ __launch_bounds__(256) void k_bucketB2(
    const u64* __restrict__ temp0, const int* __restrict__ bbase0,
    int* __restrict__ rowptr0, int* __restrict__ csrc0,
    const float* __restrict__ es1, const float* __restrict__ ed1,
    half4* __restrict__ w0, float* __restrict__ denom1,
    const u64* __restrict__ temp1, const int* __restrict__ bbase1,
    int* __restrict__ rowptr1, int* __restrict__ csrc1, int N, int nb) {
  const int g0 = (blockIdx.x < nb);
  const u64* temp = g0 ? temp0 : temp1;
  const int* bbase = g0 ? bbase0 : bbase1;
  int* rowptr = g0 ? rowptr0 : rowptr1;
  int* csrc   = g0 ? csrc0 : csrc1;
  const int b = g0 ? blockIdx.x : blockIdx.x - nb;
  __shared__ int lcnt[128];
  __shared__ int lcur[128];
  __shared__ int wt4[4];
  __shared__ float lden[512];
  __shared__ float ledv[512];
  const int tid = threadIdx.x;
  const int d0 = b << 7;
  const int d1 = min(d0 + 128, N);
  const int lo = bbase[b], hi = bbase[b+1];
  if (tid < 128) lcnt[tid] = 0;
  if (g0) {
    for (int i = tid; i < 512; i += 256) lden[i] = 0.f;
    for (int i = tid; i < (d1 - d0)*4; i += 256) ledv[i] = ed1[d0*4 + i];
  }
  __syncthreads();
  for (int k = lo + tid; k < hi; k += 256)
    atomicAdd(&lcnt[(int)(temp[k] >> 32) - d0], 1);
  __syncthreads();
  int v = (tid < 128) ? lcnt[tid] : 0;
  const int lane = tid & 63, w = tid >> 6;
  int inc = v;
  #pragma unroll
  for (int o = 1; o < 64; o <<= 1) { int t = __shfl_up(inc, o); if (lane >= o) inc += t; }
  if (lane == 63) wt4[w] = inc;
  __syncthreads();
  int woff = 0;
  for (int i = 0; i < w; ++i) woff += wt4[i];
  int excl = lo + woff + inc - v;
  if (tid < d1 - d0) { rowptr[d0 + tid] = excl; lcur[tid] = excl; }
  if (b == nb-1 && tid == 0) rowptr[N] = hi;
  __syncthreads();
  for (int k = lo + tid; k < hi; k += 256) {
    u64 p = temp[k];
    int d = (int)(p >> 32);
    int s = (int)(unsigned)p;
    int pos = atomicAdd(&lcur[d - d0], 1);
    csrc[pos] = s;
    if (g0) {
      float4 e = *(const float4*)(es1 + (size_t)s*4);
      int ld = (d - d0)*4;
      half4 wh;
      wh.x = (_Float16)__expf(lrelu02(e.x + ledv[ld+0]));
      wh.y = (_Float16)__expf(lrelu02(e.y + ledv[ld+1]));
      wh.z = (_Float16)__expf(lrelu02(e.z + ledv[ld+2]));
      wh.w = (_Float16)__expf(lrelu02(e.w + ledv[ld+3]));
      w0[pos] = wh;
      atomicAdd(&lden[ld+0], (float)wh.x);
      atomicAdd(&lden[ld+1], (float)wh.y);
      atomicAdd(&lden[ld+2], (float)wh.z);
      atomicAdd(&lden[ld+3], (float)wh.w);
    }
  }
  __syncthreads();
  if (g0)
    for (int i = tid; i < (d1 - d0)*4; i += 256) denom1[d0*4 + i] = lden[i];
}

// ------------- w1a/w1b [128][4]: w1a[k][h] = sum_j W1[k][h*64+j]*a_src[h][j] -------------
__global__ __launch_bounds__(512) void k_w1ab(
    const float* __restrict__ W1, const float* __restrict__ a_src,
    const float* __restrict__ a_dst, float* __restrict__ w1a, float* __restrict__ w1b) {
  const int t = threadIdx.x;
  const int k = t & 127, h = t >> 7;
  float sa = 0.f, sb = 0.f;
  const float* wrow = W1 + (size_t)k*256 + h*64;
  const float* as = a_src + h*64;
  const float* ad = a_dst + h*64;
  #pragma unroll 8
  for (int j = 0; j < 64; ++j) { sa += wrow[j]*as[j]; sb += wrow[j]*ad[j]; }
  w1a[k*4 + h] = sa;
  w1b[k*4 + h] = sb;
}

// ------------- lx = logmap0(x) fp16 [N,128]; es1/ed1 [N,4] = lx @ w1a/w1b -------------
__global__ void k_lx_es(const float* __restrict__ x,
                        const float* __restrict__ w1a, const float* __restrict__ w1b,
                        _Float16* __restrict__ lxh,
                        float* __restrict__ es, float* __restrict__ ed, int N) {
  int tidg = blockIdx.x*blockDim.x + threadIdx.x;
  int wid = tidg >> 6, lane = tidg & 63;
  int nw = (gridDim.x * blockDim.x) >> 6;
  for (int row = wid; row < N; row += nw) {
    float2 v = *(const float2*)(x + (size_t)row*128 + lane*2);
    float ss = v.x*v.x + v.y*v.y;
    #pragma unroll
    for (int o = 32; o; o >>= 1) ss += __shfl_xor(ss, o);
    float n  = fmaxf(sqrtf(ss), EPSF);
    float nc = fminf(n, 1.f - 1e-5f);
    float sc = atanhf(nc) / n;                 // logmap0 scale
    float l0 = v.x*sc, l1 = v.y*sc;
    half2v hv; hv.x = (_Float16)l0; hv.y = (_Float16)l1;
    *(half2v*)(lxh + (size_t)row*128 + lane*2) = hv;
    float4 a0 = *(const float4*)(w1a + (lane*2)*4);
    float4 a1 = *(const float4*)(w1a + (lane*2+1)*4);
    float4 b0 = *(const float4*)(w1b + (lane*2)*4);
    float4 b1 = *(const float4*)(w1b + (lane*2+1)*4);
    float4 ps, pd;
    ps.x = l0*a0.x + l1*a1.x; ps.y = l0*a0.y + l1*a1.y;
    ps.z = l0*a0.z + l1*a1.z; ps.w = l0*a0.w + l1*a1.w;
    pd.x = l0*b0.x + l1*b1.x; pd.y = l0*b0.y + l1*b1.y;
    pd.z = l0*b0.z + l1*b1.z; pd.w = l0*b0.w + l1*b1.w;
    #pragma unroll
    for (int o = 32; o; o >>= 1) {
      ps.x += __shfl_xor(ps.x, o); ps.y += __shfl_xor(ps.y, o);
      ps.z += __shfl_xor(ps.z, o); ps.w += __shfl_xor(ps.w, o);
      pd.x += __shfl_xor(pd.x, o); pd.y += __shfl_xor(pd.y, o);
      pd.z += __shfl_xor(pd.z, o); pd.w += __shfl_xor(pd.w, o);
    }
    if (lane == 0) {
      *(float4*)(es + (size_t)row*4) = ps;
      *(float4*)(ed + (size_t)row*4) = pd;
    }
  }
}

// ------------- layer1 aggregation in lx-domain: pure gather+FMA (weights precomputed)
//   u[N,4,128] fp16 = per-head weighted mean of lx[src]
__global__ void k_agg1_csr(const int* __restrict__ rowptr, const int* __restrict__ csrc,
                           const half4* __restrict__ w0, const float* __restrict__ denom,
                           const _Float16* __restrict__ lxh, _Float16* __restrict__ uh,
                           int N) {
  int tidg = blockIdx.x*blockDim.x + threadIdx.x;
  int wid = tidg >> 6, lane = tidg & 63;
  int nw = (gridDim.x * blockDim.x) >> 6;
  for (int d = wid; d < N; d += nw) {
    const int beg = rowptr[d], end = rowptr[d+1];
    float accx[4] = {0,0,0,0}, accy[4] = {0,0,0,0};
    int k = beg;
    for (; k + 4 <= end; k += 4) {
      int s0 = csrc[k], s1 = csrc[k+1], s2 = csrc[k+2], s3 = csrc[k+3];
      half4 wA = w0[k], wB = w0[k+1], wC = w0[k+2], wD = w0[k+3];
      half2v v0 = *(const half2v*)(lxh + (size_t)s0*128 + lane*2);
      half2v v1 = *(const half2v*)(lxh + (size_t)s1*128 + lane*2);
      half2v v2 = *(const half2v*)(lxh + (size_t)s2*128 + lane*2);
      half2v v3 = *(const half2v*)(lxh + (size_t)s3*128 + lane*2);
      float wa[4] = {(float)wA.x,(float)wA.y,(float)wA.z,(float)wA.w};
      float wb[4] = {(float)wB.x,(float)wB.y,(float)wB.z,(float)wB.w};
      float wc[4] = {(float)wC.x,(float)wC.y,(float)wC.z,(float)wC.w};
      float wd[4] = {(float)wD.x,(float)wD.y,(float)wD.z,(float)wD.w};
      float vx[4] = {(float)v0.x,(float)v1.x,(float)v2.x,(float)v3.x};
      float vy[4] = {(float)v0.y,(float)v1.y,(float)v2.y,(float)v3.y};
      #pragma unroll
      for (int h = 0; h < 4; ++h) {
        accx[h] += wa[h]*vx[0] + wb[h]*vx[1] + wc[h]*vx[2] + wd[h]*vx[3];
        accy[h] += wa[h]*vy[0] + wb[h]*vy[1] + wc[h]*vy[2] + wd[h]*vy[3];
      }
    }
    for (; k < end; ++k) {
      int s = csrc[k];
      half4 wA = w0[k];
      half2v v0 = *(const half2v*)(lxh + (size_t)s*128 + lane*2);
      float wa[4] = {(float)wA.x,(float)wA.y,(float)wA.z,(float)wA.w};
      float fx = (float)v0.x, fy = (float)v0.y;
      #pragma unroll
      for (int h = 0; h < 4; ++h) { accx[h] += wa[h]*fx; accy[h] += wa[h]*fy; }
    }
    const float4 dn = *(const float4*)(denom + (size_t)d*4);
    float inv[4] = {1.f/(dn.x+1e-16f), 1.f/(dn.y+1e-16f),
                    1.f/(dn.z+1e-16f), 1.f/(dn.w+1e-16f)};
    #pragma unroll
    for (int h = 0; h < 4; ++h) {
      half2v o2; o2.x = (_Float16)(accx[h]*inv[h]); o2.y = (_Float16)(accy[h]*inv[h]);
      *(half2v*)(uh + (size_t)d*512 + h*128 + lane*2) = o2;
    }
  }
}

// ------------- fused layer-1 GEMM + maps + layer-2 GEMM (t2 stays in LDS) -------------
// phase1: t2 = expmap/logmap-scale( u @ W1 ) per head -> LDS fp16 [16][4][68]
// phase2: h2 = t2 @ W2 (k-sliced across 4 lane-groups) + es2/ed2
#define HPAD 132    // halves per head in u-tile LDS (4*HPAD = 528 per row)
#define SL 68       // halves per k-slice in t2 LDS (4*SL = 272 per row)
__global__ __launch_bounds__(256) void k_layer12(
    const _Float16* __restrict__ uh, const float* __restrict__ W1,
    const float* __restrict__ W2,
    const float* __restrict__ a_src, const float* __restrict__ a_dst,
    _Float16* __restrict__ h2h, float* __restrict__ es, float* __restrict__ ed, int N) {
  __shared__ _Float16 th[16*4*HPAD];            // 16.9 KB u-tile
  __shared__ _Float16 t2l[16*4*SL];             // 8.7 KB t2-tile
  const int tid = threadIdx.x;
  const int block0 = blockIdx.x * 16;
  const int vrows = (block0 < N) ? min(16, N - block0) : 0;
  for (int i = tid; i < 2048; i += 256) {
    int r = i >> 7, rem = i & 127;
    int h = rem >> 5, c = rem & 31;
    uint2 v = make_uint2(0u, 0u);
    if (r < vrows)
      v = *(const uint2*)(uh + (size_t)(block0 + r)*512 + h*128 + c*4);
    *(uint2*)(th + r*(4*HPAD) + h*HPAD + c*4) = v;
  }
  __syncthreads();
  const int wv = tid >> 6, lane = tid & 63;
  // ---- phase 1: wave owns rows wv*4..+3; lane owns cols j..j+3 ----
  {
    const int j = lane * 4;
    const int head = lane >> 4;
    const int r0 = wv * 4;
    float4 acc[4];
    #pragma unroll
    for (int r = 0; r < 4; ++r) acc[r] = make_float4(0.f,0.f,0.f,0.f);
    for (int k = 0; k < 128; k += 4) {
      float4 w0 = *(const float4*)(W1 + (size_t)(k+0)*256 + j);
      float4 w1 = *(const float4*)(W1 + (size_t)(k+1)*256 + j);
      float4 w2 = *(const float4*)(W1 + (size_t)(k+2)*256 + j);
      float4 w3 = *(const float4*)(W1 + (size_t)(k+3)*256 + j);
      #pragma unroll
      for (int r = 0; r < 4; ++r) {
        half4 tvh = *(const half4*)(th + (r0 + r)*(4*HPAD) + head*HPAD + k);
        float tx = (float)tvh.x, ty = (float)tvh.y, tz = (float)tvh.z, tw = (float)tvh.w;
        acc[r].x += tx*w0.x + ty*w1.x + tz*w2.x + tw*w3.x;
        acc[r].y += tx*w0.y + ty*w1.y + tz*w2.y + tw*w3.y;
        acc[r].z += tx*w0.z + ty*w1.z + tz*w2.z + tw*w3.z;
        acc[r].w += tx*w0.w + ty*w1.w + tz*w2.w + tw*w3.w;
      }
    }
    #pragma unroll
    for (int r = 0; r < 4; ++r) {
      float4 a = acc[r];
      float ss = a.x*a.x + a.y*a.y + a.z*a.z + a.w*a.w;
      #pragma unroll
      for (int o = 32; o; o >>= 1) ss += __shfl_xor(ss, o);
      float n  = fmaxf(sqrtf(ss), EPSF);
      float s1 = tanhf(n) / n;                  // expmap0 scale
      float n2 = fmaxf(s1 * n, EPSF);           // = tanh(n), clamped
      float nc = fminf(n2, 1.f - 1e-5f);
      float sc = s1 * atanhf(nc) / n2;
      half4 o4; o4.x = (_Float16)(a.x*sc); o4.y = (_Float16)(a.y*sc);
                o4.z = (_Float16)(a.z*sc); o4.w = (_Float16)(a.w*sc);
      // j = slice*64 + kk ; slice = j>>6, kk = j&63
      *(half4*)(t2l + (r0 + r)*(4*SL) + (j >> 6)*SL + (j & 63)) = o4;
    }
  }
  __syncthreads();
  // ---- phase 2: lane owns cols cj..cj+3, k-slice g*64..+63; wave rows wv*4..+3 ----
  {
    const int g = lane >> 4;
    const int cj = (lane & 15) * 4;
    const int r0 = wv * 4;
    float4 a2[4];
    #pragma unroll
    for (int r = 0; r < 4; ++r) a2[r] = make_float4(0.f,0.f,0.f,0.f);
    const int k0 = g * 64;
    for (int kk = 0; kk < 64; kk += 4) {
      int k = k0 + kk;
      float4 w0 = *(const float4*)(W2 + (size_t)(k+0)*64 + cj);
      float4 w1 = *(const float4*)(W2 + (size_t)(k+1)*64 + cj);
      float4 w2 = *(const float4*)(W2 + (size_t)(k+2)*64 + cj);
      float4 w3 = *(const float4*)(W2 + (size_t)(k+3)*64 + cj);
      #pragma unroll
      for (int r = 0; r < 4; ++r) {
        half4 tvh = *(const half4*)(t2l + (r0 + r)*(4*SL) + g*SL + kk);
        float tx = (float)tvh.x, ty = (float)tvh.y, tz = (float)tvh.z, tw = (float)tvh.w;
        a2[r].x += tx*w0.x + ty*w1.x + tz*w2.x + tw*w3.x;
        a2[r].y += tx*w0.y + ty*w1.y + tz*w2.y + tw*w3.y;
        a2[r].z += tx*w0.z + ty*w1.z + tz*w2.z + tw*w3.z;
        a2[r].w += tx*w0.w + ty*w1.w + tz*w2.w + tw*w3.w;
      }
    }
    // reduce k-slices across the 4 groups (lane^16, lane^32)
    #pragma unroll
    for (int r = 0; r < 4; ++r) {
      #pragma unroll
      for (int o = 16; o <= 32; o <<= 1) {
        a2[r].x += __shfl_xor(a2[r].x, o);
        a2[r].y += __shfl_xor(a2[r].y, o);
        a2[r].z += __shfl_xor(a2[r].z, o);
        a2[r].w += __shfl_xor(a2[r].w, o);
      }
    }
    const float4 as4 = *(const float4*)(a_src + cj);
    const float4 ad4 = *(const float4*)(a_dst + cj);
    #pragma unroll
    for (int r = 0; r < 4; ++r) {
      int row = block0 + r0 + r;
      if (row < N) {
        float4 a = a2[r];
        if (g == 0) {
          half4 hv; hv.x = (_Float16)a.x; hv.y = (_Float16)a.y;
                    hv.z = (_Float16)a.z; hv.w = (_Float16)a.w;
          *(half4*)(h2h + (size_t)row*64 + cj) = hv;
        }
        float ps = a.x*as4.x + a.y*as4.y + a.z*as4.z + a.w*as4.w;
        float pd = a.x*ad4.x + a.y*ad4.y + a.z*ad4.z + a.w*ad4.w;
        #pragma unroll
        for (int o = 8; o; o >>= 1) { ps += __shfl_xor(ps, o); pd += __shfl_xor(pd, o); }
        if (lane == 0) { es[row] = ps; ed[row] = pd; }
      }
    }
  }
}

// ------------- layer2 aggregation (CSR, wave per dst, unroll-4) + fused expmap0 ----------
__global__ void k_agg2_csr(const int* __restrict__ rowptr, const int* __restrict__ csrc,
                           const float* __restrict__ es, const float* __restrict__ ed,
                           const _Float16* __restrict__ h2h, float* __restrict__ out, int N) {
  int tidg = blockIdx.x*blockDim.x + threadIdx.x;
  int wid = tidg >> 6, lane = tidg & 63;
  int nw = (gridDim.x * blockDim.x) >> 6;
  for (int d = wid; d < N; d += nw) {
    const int beg = rowptr[d], end = rowptr[d+1];
    const float edv = ed[d];
    float acc = 0.f, wsum = 0.f;
    int k = beg;
    for (; k + 4 <= end; k += 4) {
      int s0 = csrc[k], s1 = csrc[k+1], s2 = csrc[k+2], s3 = csrc[k+3];
      float w0 = __expf(lrelu02(es[s0] + edv));
      float w1 = __expf(lrelu02(es[s1] + edv));
      float w2 = __expf(lrelu02(es[s2] + edv));
      float w3 = __expf(lrelu02(es[s3] + edv));
      float x0 = (float)h2h[(size_t)s0*64 + lane];
      float x1 = (float)h2h[(size_t)s1*64 + lane];
      float x2 = (float)h2h[(size_t)s2*64 + lane];
      float x3 = (float)h2h[(size_t)s3*64 + lane];
      wsum += (w0 + w1) + (w2 + w3);
      acc += w0*x0 + w1*x1 + w2*x2 + w3*x3;
    }
    for (; k < end; ++k) {
      int s = csrc[k];
      float w = __expf(lrelu02(es[s] + edv));
      wsum += w;
      acc += w * (float)h2h[(size_t)s*64 + lane];
    }
    float a = acc / (wsum + 1e-16f);
    float ss = a*a;
    #pragma unroll
    for (int o = 32; o; o >>= 1) ss += __shfl_xor(ss, o);
    float n  = fmaxf(sqrtf(ss), EPSF);
    float sc = tanhf(n) / n;                    // expmap0 scale
    out[(size_t)d*64 + lane] = a * sc;
  }
}

extern "C" void kernel_launch(void* const* d_in, const int* in_sizes, int n_in,
                              void* d_out, int out_size, void* d_ws, size_t ws_size,
                              hipStream_t stream) {
  const float* x      = (const float*)d_in[0];
  const float* W1     = (const float*)d_in[1];
  const float* a_src1 = (const float*)d_in[2];
  const float* a_dst1 = (const float*)d_in[3];
  const float* W2     = (const float*)d_in[4];
  const float* a_src2 = (const float*)d_in[5];
  const float* a_dst2 = (const float*)d_in[6];
  const int*   ei0    = (const int*)d_in[7];
  const int*   ei1    = (const int*)d_in[8];
  const int N  = in_sizes[0] / 128;
  const int E0 = in_sizes[7] / 2;
  const int E1 = in_sizes[8] / 2;
  const int* src0 = ei0;  const int* dst0 = ei0 + E0;
  const int* src1 = ei1;  const int* dst1 = ei1 + E1;
  float* out = (float*)d_out;
  const int nb = (N + 127) >> 7;

  float* ws = (float*)d_ws;
  size_t o = 0;
  float* es1   = ws + o; o += (size_t)N*4;
  float* ed1   = ws + o; o += (size_t)N*4;
  float* es2   = ws + o; o += (size_t)N;
  float* ed2   = ws + o; o += (size_t)N;
  float* denom1= ws + o; o += (size_t)N*4;
  float* w1a   = ws + o; o += 512;
  float* w1b   = ws + o; o += 512;
  _Float16* lxh = (_Float16*)(ws + o); o += (size_t)N*64;   // N*128 halves
  _Float16* uh  = (_Float16*)(ws + o); o += (size_t)N*256;  // N*512 halves
  _Float16* h2h = (_Float16*)(ws + o); o += (size_t)N*32;   // N*64 halves
  o += (o & 1);                                             // 8B align
  half4* w0    = (half4*)(ws + o); o += (size_t)E0*2;       // E0*4 halves
  u64* temp0 = (u64*)(ws + o); o += (size_t)E0*2;
  u64* temp1 = (u64*)(ws + o); o += (size_t)E1*2;
  int* iws = (int*)(ws + o);
  size_t io = 0;
  int* rowptr0 = iws + io; io += N + 1;
  int* rowptr1 = iws + io; io += N + 1;
  int* bcnt0   = iws + io; io += NBMAX;  // bcnt0/bcnt1 adjacent: one memset
  int* bcnt1   = iws + io; io += NBMAX;
  int* bbase0  = iws + io; io += NBMAX + 1;
  int* bbase1  = iws + io; io += NBMAX + 1;
  int* bcur0   = iws + io; io += NBMAX;
  int* bcur1   = iws + io; io += NBMAX;
  int* csrc0   = iws + io; io += E0;
  int* csrc1   = iws + io; io += E1;

  dim3 blk(256);
  const int blocksA0 = (E0 + 4095) / 4096;
  const int blocksA1 = (E1 + 4095) / 4096;
  // independent precompute (must precede k_bucketB2: it consumes es1/ed1)
  hipMemsetAsync(bcnt0, 0, 2*NBMAX*sizeof(int), stream);
  k_w1ab   <<<1, 512, 0, stream>>>(W1, a_src1, a_dst1, w1a, w1b);
  k_lx_es  <<<2048, blk, 0, stream>>>(x, w1a, w1b, lxh, es1, ed1, N);
  // CSR build (+ graph-0 edge weights & denominators fused into bucketB2)
  k_bhist  <<<1024, blk, 0, stream>>>(dst0, E0, dst1, E1, bcnt0, bcnt1, nb);
  k_bscan  <<<1, 1024, 0, stream>>>(bcnt0, bbase0, bcur0, bcnt1, bbase1, bcur1, nb);
  k_bucketA<<<blocksA0 + blocksA1, blk, 0, stream>>>(
      src0, dst0, bcur0, temp0, E0, blocksA0, src1, dst1, bcur1, temp1, E1, nb);
  k_bucketB2<<<2*nb, blk, 0, stream>>>(temp0, bbase0, rowptr0, csrc0,
                                       es1, ed1, w0, denom1,
                                       temp1, bbase1, rowptr1, csrc1, N, nb);
  // layer 1 aggregation, then fused GEMM1+maps+GEMM2
  k_agg1_csr<<<2048, blk, 0, stream>>>(rowptr0, csrc0, w0, denom1, lxh, uh, N);
  k_layer12<<<(N+15)/16, blk, 0, stream>>>(uh, W1, W2, a_src2, a_dst2,
                                           h2h, es2, ed2, N);
  // layer 2 aggregation
  k_agg2_csr<<<2048, blk, 0, stream>>>(rowptr1, csrc1, es2, ed2, h2h, out, N);
}

// Round 17
// 338.291 us; speedup vs baseline: 1.3604x; 1.3604x over previous
//
#include <hip/hip_runtime.h>

#define EPSF 1e-7f
#define NBMAX 512   // max dst-buckets (ceil(N/128)); N=50000 -> 391

typedef __attribute__((ext_vector_type(4))) _Float16 half4;
typedef unsigned long long u64;

__device__ __forceinline__ float lrelu02(float x){ return x > 0.f ? x : 0.2f*x; }

// ---------------- CSR build (bucket-local, no N-sized scan) ----------------
__global__ __launch_bounds__(256) void k_bhist(
    const int* __restrict__ dst0, int E0, const int* __restrict__ dst1, int E1,
    int* __restrict__ bcnt0, int* __restrict__ bcnt1, int nb) {
  __shared__ int h0[NBMAX], h1[NBMAX];
  const int tid = threadIdx.x;
  const int g = blockIdx.x*blockDim.x + tid;
  const int stride = gridDim.x*blockDim.x;
  for (int i = tid; i < nb; i += 256) { h0[i] = 0; h1[i] = 0; }
  __syncthreads();
  for (int i = g; i < E0; i += stride) atomicAdd(&h0[dst0[i] >> 7], 1);
  for (int i = g; i < E1; i += stride) atomicAdd(&h1[dst1[i] >> 7], 1);
  __syncthreads();
  for (int i = tid; i < nb; i += 256) {
    if (h0[i]) atomicAdd(&bcnt0[i], h0[i]);
    if (h1[i]) atomicAdd(&bcnt1[i], h1[i]);
  }
}

__global__ __launch_bounds__(1024) void k_bscan(
    const int* __restrict__ bcnt0, int* __restrict__ bbase0, int* __restrict__ bcur0,
    const int* __restrict__ bcnt1, int* __restrict__ bbase1, int* __restrict__ bcur1,
    int nb) {
  __shared__ int wt[16];
  const int tid = threadIdx.x;
  const int half = tid >> 9, idx = tid & 511;
  const int* bcnt = half ? bcnt1 : bcnt0;
  int* bbase = half ? bbase1 : bbase0;
  int* bcur  = half ? bcur1  : bcur0;
  int v = (idx < nb) ? bcnt[idx] : 0;
  const int lane = tid & 63, w = tid >> 6;
  int inc = v;
  #pragma unroll
  for (int o = 1; o < 64; o <<= 1) { int t = __shfl_up(inc, o); if (lane >= o) inc += t; }
  if (lane == 63) wt[w] = inc;
  __syncthreads();
  int woff = 0;
  for (int i = half*8; i < w; ++i) woff += wt[i];
  int excl = woff + inc - v;
  if (idx < nb) { bbase[idx] = excl; bcur[idx] = excl; }
  if (idx == nb-1) bbase[nb] = excl + v;
}

__global__ __launch_bounds__(256) void k_bucketA(
    const int* __restrict__ src0, const int* __restrict__ dst0,
    int* __restrict__ bcur0, u64* __restrict__ temp0, int E0, int blocksA0,
    const int* __restrict__ src1, const int* __restrict__ dst1,
    int* __restrict__ bcur1, u64* __restrict__ temp1, int E1, int nb) {
  const int g0 = (blockIdx.x < blocksA0);
  const int* src = g0 ? src0 : src1;
  const int* dst = g0 ? dst0 : dst1;
  int* bcur      = g0 ? bcur0 : bcur1;
  u64* temp      = g0 ? temp0 : temp1;
  const int E    = g0 ? E0 : E1;
  const int cb   = g0 ? blockIdx.x : blockIdx.x - blocksA0;
  __shared__ int hist[NBMAX];
  __shared__ int lbase[NBMAX];
  const int tid = threadIdx.x;
  const int chunk0 = cb * 4096;
  const int e_end = min(chunk0 + 4096, E);
  for (int i = tid; i < nb; i += 256) hist[i] = 0;
  __syncthreads();
  for (int i = chunk0 + tid; i < e_end; i += 256)
    atomicAdd(&hist[dst[i] >> 7], 1);
  __syncthreads();
  for (int bn = tid; bn < nb; bn += 256) {
    int c = hist[bn];
    lbase[bn] = c ? atomicAdd(&bcur[bn], c) : 0;
    hist[bn] = 0;
  }
  __syncthreads();
  for (int i = chunk0 + tid; i < e_end; i += 256) {
    int d = dst[i];
    int bn = d >> 7;
    int off = atomicAdd(&hist[bn], 1);
    temp[(size_t)lbase[bn] + off] = ((u64)(unsigned)d << 32) | (unsigned)src[i];
  }
}

// pass B: per bucket, per-dst count + local scan -> rowptr; scatter csrc.
// For graph 0 additionally: per-edge attention weights (fp16) + per-dst denominators.
__global__ __launch_bounds__(256) void k_bucketB2(
    const u64* __restrict__ temp0, const int* __restrict__ bbase0,
    int* __restrict__ rowptr0, int* __restrict__ csrc0,
    const float* __restrict__ es1, const float* __restrict__ ed1,
    half4* __restrict__ w0, float* __restrict__ denom1,
    const u64* __restrict__ temp1, const int* __restrict__ bbase1,
    int* __restrict__ rowptr1, int* __restrict__ csrc1, int N, int nb) {
  const int g0 = (blockIdx.x < nb);
  const u64* temp = g0 ? temp0 : temp1;
  const int* bbase = g0 ? bbase0 : bbase1;
  int* rowptr = g0 ? rowptr0 : rowptr1;
  int* csrc   = g0 ? csrc0 : csrc1;
  const int b = g0 ? blockIdx.x : blockIdx.x - nb;
  __shared__ int lcnt[128];
  __shared__ int lcur[128];
  __shared__ int wt4[4];
  __shared__ float lden[512];
  __shared__ float ledv[512];
  const int tid = threadIdx.x;
  const int d0 = b << 7;
  const int d1 = min(d0 + 128, N);
  const int lo = bbase[b], hi = bbase[b+1];
  if (tid < 128) lcnt[tid] = 0;
  if (g0) {
    for (int i = tid; i < 512; i += 256) lden[i] = 0.f;
    for (int i = tid; i < (d1 - d0)*4; i += 256) ledv[i] = ed1[d0*4 + i];
  }
  __syncthreads();
  for (int k = lo + tid; k < hi; k += 256)
    atomicAdd(&lcnt[(int)(temp[k] >> 32) - d0], 1);
  __syncthreads();
  int v = (tid < 128) ? lcnt[tid] : 0;
  const int lane = tid & 63, w = tid >> 6;
  int inc = v;
  #pragma unroll
  for (int o = 1; o < 64; o <<= 1) { int t = __shfl_up(inc, o); if (lane >= o) inc += t; }
  if (lane == 63) wt4[w] = inc;
  __syncthreads();
  int woff = 0;
  for (int i = 0; i < w; ++i) woff += wt4[i];
  int excl = lo + woff + inc - v;
  if (tid < d1 - d0) { rowptr[d0 + tid] = excl; lcur[tid] = excl; }
  if (b == nb-1 && tid == 0) rowptr[N] = hi;
  __syncthreads();
  for (int k = lo + tid; k < hi; k += 256) {
    u64 p = temp[k];
    int d = (int)(p >> 32);
    int s = (int)(unsigned)p;
    int pos = atomicAdd(&lcur[d - d0], 1);
    csrc[pos] = s;
    if (g0) {
      float4 e = *(const float4*)(es1 + (size_t)s*4);
      int ld = (d - d0)*4;
      half4 wh;
      wh.x = (_Float16)__expf(lrelu02(e.x + ledv[ld+0]));
      wh.y = (_Float16)__expf(lrelu02(e.y + ledv[ld+1]));
      wh.z = (_Float16)__expf(lrelu02(e.z + ledv[ld+2]));
      wh.w = (_Float16)__expf(lrelu02(e.w + ledv[ld+3]));
      w0[pos] = wh;
      atomicAdd(&lden[ld+0], (float)wh.x);
      atomicAdd(&lden[ld+1], (float)wh.y);
      atomicAdd(&lden[ld+2], (float)wh.z);
      atomicAdd(&lden[ld+3], (float)wh.w);
    }
  }
  __syncthreads();
  if (g0)
    for (int i = tid; i < (d1 - d0)*4; i += 256) denom1[d0*4 + i] = lden[i];
}

// ------------- layer1: logmap0(x) @ W1 -> h1 (fp16) [N,256]; es1/ed1 [N,4]
//   j-blocked: lane owns cols j=lane*4..lane*4+3; wave owns 8 rows; block = 32 rows
__global__ __launch_bounds__(256) void k_gemm1(
    const float* __restrict__ x, const float* __restrict__ W1,
    const float* __restrict__ a_src, const float* __restrict__ a_dst,
    _Float16* __restrict__ h1h, float* __restrict__ es, float* __restrict__ ed, int N) {
  __shared__ float t[32][128];          // 16 KB
  const int tid = threadIdx.x;
  const int block0 = blockIdx.x * 32;
  #pragma unroll
  for (int p = 0; p < 4; ++p) {
    const int r = (tid >> 5) + p*8, c = (tid & 31) * 4;
    const int row = block0 + r;
    float4 v = make_float4(0.f,0.f,0.f,0.f);
    if (row < N) v = *(const float4*)(x + (size_t)row*128 + c);
    float ss = v.x*v.x + v.y*v.y + v.z*v.z + v.w*v.w;
    #pragma unroll
    for (int o = 16; o; o >>= 1) ss += __shfl_xor(ss, o);
    float n  = fmaxf(sqrtf(ss), EPSF);
    float nc = fminf(n, 1.f - 1e-5f);
    float sc = atanhf(nc) / n;                 // logmap0 scale
    *(float4*)&t[r][c] = make_float4(v.x*sc, v.y*sc, v.z*sc, v.w*sc);
  }
  __syncthreads();

  const int wv = tid >> 6, lane = tid & 63;
  const int j = lane * 4;               // columns j..j+3
  const int r0 = wv * 8;                // wave's 8 rows
  float4 acc[8];
  #pragma unroll
  for (int r = 0; r < 8; ++r) acc[r] = make_float4(0.f,0.f,0.f,0.f);
  for (int k = 0; k < 128; k += 4) {
    float4 w0 = *(const float4*)(W1 + (size_t)(k+0)*256 + j);
    float4 w1 = *(const float4*)(W1 + (size_t)(k+1)*256 + j);
    float4 w2 = *(const float4*)(W1 + (size_t)(k+2)*256 + j);
    float4 w3 = *(const float4*)(W1 + (size_t)(k+3)*256 + j);
    #pragma unroll
    for (int r = 0; r < 8; ++r) {
      float4 tv = *(const float4*)&t[r0 + r][k];   // wave-uniform addr: broadcast
      acc[r].x += tv.x*w0.x + tv.y*w1.x + tv.z*w2.x + tv.w*w3.x;
      acc[r].y += tv.x*w0.y + tv.y*w1.y + tv.z*w2.y + tv.w*w3.y;
      acc[r].z += tv.x*w0.z + tv.y*w1.z + tv.z*w2.z + tv.w*w3.z;
      acc[r].w += tv.x*w0.w + tv.y*w1.w + tv.z*w2.w + tv.w*w3.w;
    }
  }
  const int head = lane >> 4;
  const float4 as4 = *(const float4*)(a_src + j);   // j = head*64 + (lane&15)*4
  const float4 ad4 = *(const float4*)(a_dst + j);
  #pragma unroll
  for (int r = 0; r < 8; ++r) {
    int row = block0 + r0 + r;
    if (row >= N) break;
    float4 a = acc[r];
    half4 hv; hv.x = (_Float16)a.x; hv.y = (_Float16)a.y;
              hv.z = (_Float16)a.z; hv.w = (_Float16)a.w;
    *(half4*)(h1h + (size_t)row*256 + j) = hv;
    float ps = a.x*as4.x + a.y*as4.y + a.z*as4.z + a.w*as4.w;
    float pd = a.x*ad4.x + a.y*ad4.y + a.z*ad4.z + a.w*ad4.w;
    #pragma unroll
    for (int o = 8; o; o >>= 1) { ps += __shfl_xor(ps, o); pd += __shfl_xor(pd, o); }
    if ((lane & 15) == 0) { es[row*4 + head] = ps; ed[row*4 + head] = pd; }
  }
}

// ------------- layer1 aggregation: pure gather+FMA (weights precomputed in bucketB2)
//   wave per dst; lane owns cols lane*4..+3 (head = lane>>4); unroll-4
//   output t2h fp16 with fused expmap0/logmap0
__global__ void k_agg1_csr(const int* __restrict__ rowptr, const int* __restrict__ csrc,
                           const half4* __restrict__ w0, const float* __restrict__ denom,
                           const _Float16* __restrict__ h1h, _Float16* __restrict__ t2h,
                           int N) {
  int tidg = blockIdx.x*blockDim.x + threadIdx.x;
  int wid = tidg >> 6, lane = tidg & 63;
  int nw = (gridDim.x * blockDim.x) >> 6;
  const int h = lane >> 4;
  const _Float16* wp = (const _Float16*)w0;
  for (int d = wid; d < N; d += nw) {
    const int beg = rowptr[d], end = rowptr[d+1];
    float4 acc = make_float4(0.f,0.f,0.f,0.f);
    int k = beg;
    for (; k + 4 <= end; k += 4) {
      int s0 = csrc[k], s1 = csrc[k+1], s2 = csrc[k+2], s3 = csrc[k+3];
      float wa = (float)wp[(size_t)(k+0)*4 + h];
      float wb = (float)wp[(size_t)(k+1)*4 + h];
      float wc = (float)wp[(size_t)(k+2)*4 + h];
      float wd = (float)wp[(size_t)(k+3)*4 + h];
      half4 v0 = *(const half4*)(h1h + (size_t)s0*256 + lane*4);
      half4 v1 = *(const half4*)(h1h + (size_t)s1*256 + lane*4);
      half4 v2 = *(const half4*)(h1h + (size_t)s2*256 + lane*4);
      half4 v3 = *(const half4*)(h1h + (size_t)s3*256 + lane*4);
      acc.x += wa*(float)v0.x + wb*(float)v1.x + wc*(float)v2.x + wd*(float)v3.x;
      acc.y += wa*(float)v0.y + wb*(float)v1.y + wc*(float)v2.y + wd*(float)v3.y;
      acc.z += wa*(float)v0.z + wb*(float)v1.z + wc*(float)v2.z + wd*(float)v3.z;
      acc.w += wa*(float)v0.w + wb*(float)v1.w + wc*(float)v2.w + wd*(float)v3.w;
    }
    for (; k < end; ++k) {
      int s = csrc[k];
      float wa = (float)wp[(size_t)k*4 + h];
      half4 hv = *(const half4*)(h1h + (size_t)s*256 + lane*4);
      acc.x += wa*(float)hv.x; acc.y += wa*(float)hv.y;
      acc.z += wa*(float)hv.z; acc.w += wa*(float)hv.w;
    }
    float inv = 1.f / (denom[(size_t)d*4 + h] + 1e-16f);
    float ax = acc.x*inv, ay = acc.y*inv, az = acc.z*inv, aw = acc.w*inv;
    // fused t2 = logmap0(expmap0(agg)) over the 256-dim row
    float ss = ax*ax + ay*ay + az*az + aw*aw;
    #pragma unroll
    for (int o = 32; o; o >>= 1) ss += __shfl_xor(ss, o);
    float n  = fmaxf(sqrtf(ss), EPSF);
    float s1 = tanhf(n) / n;                    // expmap0 scale
    float n2 = fmaxf(s1 * n, EPSF);             // = tanh(n), clamped
    float nc = fminf(n2, 1.f - 1e-5f);
    float sc = s1 * atanhf(nc) / n2;
    half4 o4; o4.x = (_Float16)(ax*sc); o4.y = (_Float16)(ay*sc);
              o4.z = (_Float16)(az*sc); o4.w = (_Float16)(aw*sc);
    *(half4*)(t2h + (size_t)d*256 + lane*4) = o4;
  }
}

// ------------- layer2: t2h (fp16) [N,256] @ W2 [256,64] -> h2 (fp16); es2/ed2 [N]
//   block = 32 rows; wave owns 8 rows (rg-pairs); lane owns cols jj=(lane&15)*4
#define T2PAD 260
__global__ __launch_bounds__(256) void k_gemm2(
    const _Float16* __restrict__ t2h, const float* __restrict__ W2,
    const float* __restrict__ a_src, const float* __restrict__ a_dst,
    _Float16* __restrict__ h2h, float* __restrict__ es, float* __restrict__ ed, int N) {
  __shared__ float tile[32*T2PAD];              // ~33 KB, padded rows (bank spread)
  const int tid = threadIdx.x;
  const int block0 = blockIdx.x * 32;
  int validq = (block0 < N ? ((N - block0 < 32) ? (N - block0) : 32) : 0) * 64;
  const half4* srcp = (const half4*)(t2h + (size_t)block0 * 256);
  #pragma unroll
  for (int i0 = 0; i0 < 2048; i0 += 256) {
    int i = i0 + tid;
    half4 v; v.x = v.y = v.z = v.w = (_Float16)0.f;
    if (i < validq) v = srcp[i];
    int r = i >> 6, c = (i & 63) * 4;
    *(float4*)&tile[r*T2PAD + c] =
        make_float4((float)v.x, (float)v.y, (float)v.z, (float)v.w);
  }
  __syncthreads();
  const int wv = tid >> 6, lane = tid & 63;
  const int jj = (lane & 15) * 4;               // columns jj..jj+3
  const int rg = lane >> 4;                     // rowgroup 0..3
  const int rbase = wv*8 + rg*2;                // wave's rows: rbase, rbase+1
  float4 acc[2];
  acc[0] = make_float4(0.f,0.f,0.f,0.f);
  acc[1] = make_float4(0.f,0.f,0.f,0.f);
  for (int k = 0; k < 256; k += 4) {
    float4 w0 = *(const float4*)(W2 + (size_t)(k+0)*64 + jj);
    float4 w1 = *(const float4*)(W2 + (size_t)(k+1)*64 + jj);
    float4 w2 = *(const float4*)(W2 + (size_t)(k+2)*64 + jj);
    float4 w3 = *(const float4*)(W2 + (size_t)(k+3)*64 + jj);
    #pragma unroll
    for (int rr = 0; rr < 2; ++rr) {
      float4 tv = *(const float4*)&tile[(rbase + rr)*T2PAD + k]; // 16-lane broadcast
      acc[rr].x += tv.x*w0.x + tv.y*w1.x + tv.z*w2.x + tv.w*w3.x;
      acc[rr].y += tv.x*w0.y + tv.y*w1.y + tv.z*w2.y + tv.w*w3.y;
      acc[rr].z += tv.x*w0.z + tv.y*w1.z + tv.z*w2.z + tv.w*w3.z;
      acc[rr].w += tv.x*w0.w + tv.y*w1.w + tv.z*w2.w + tv.w*w3.w;
    }
  }
  const float4 as4 = *(const float4*)(a_src + jj);
  const float4 ad4 = *(const float4*)(a_dst + jj);
  #pragma unroll
  for (int rr = 0; rr < 2; ++rr) {
    int row = block0 + rbase + rr;
    if (row < N) {
      float4 a = acc[rr];
      half4 hv; hv.x = (_Float16)a.x; hv.y = (_Float16)a.y;
                hv.z = (_Float16)a.z; hv.w = (_Float16)a.w;
      *(half4*)(h2h + (size_t)row*64 + jj) = hv;
      float ps = a.x*as4.x + a.y*as4.y + a.z*as4.z + a.w*as4.w;
      float pd = a.x*ad4.x + a.y*ad4.y + a.z*ad4.z + a.w*ad4.w;
      #pragma unroll
      for (int o = 8; o; o >>= 1) { ps += __shfl_xor(ps, o); pd += __shfl_xor(pd, o); }
      if ((lane & 15) == 0) { es[row] = ps; ed[row] = pd; }
    }
  }
}

// ------------- layer2 aggregation (CSR, wave per dst, unroll-4) + fused expmap0 ----------
__global__ void k_agg2_csr(const int* __restrict__ rowptr, const int* __restrict__ csrc,
                           const float* __restrict__ es, const float* __restrict__ ed,
                           const _Float16* __restrict__ h2h, float* __restrict__ out, int N) {
  int tidg = blockIdx.x*blockDim.x + threadIdx.x;
  int wid = tidg >> 6, lane = tidg & 63;
  int nw = (gridDim.x * blockDim.x) >> 6;
  for (int d = wid; d < N; d += nw) {
    const int beg = rowptr[d], end = rowptr[d+1];
    const float edv = ed[d];
    float acc = 0.f, wsum = 0.f;
    int k = beg;
    for (; k + 4 <= end; k += 4) {
      int s0 = csrc[k], s1 = csrc[k+1], s2 = csrc[k+2], s3 = csrc[k+3];
      float w0 = __expf(lrelu02(es[s0] + edv));
      float w1 = __expf(lrelu02(es[s1] + edv));
      float w2 = __expf(lrelu02(es[s2] + edv));
      float w3 = __expf(lrelu02(es[s3] + edv));
      float x0 = (float)h2h[(size_t)s0*64 + lane];
      float x1 = (float)h2h[(size_t)s1*64 + lane];
      float x2 = (float)h2h[(size_t)s2*64 + lane];
      float x3 = (float)h2h[(size_t)s3*64 + lane];
      wsum += (w0 + w1) + (w2 + w3);
      acc += w0*x0 + w1*x1 + w2*x2 + w3*x3;
    }
    for (; k < end; ++k) {
      int s = csrc[k];
      float w = __expf(lrelu02(es[s] + edv));
      wsum += w;
      acc += w * (float)h2h[(size_t)s*64 + lane];
    }
    float a = acc / (wsum + 1e-16f);
    float ss = a*a;
    #pragma unroll
    for (int o = 32; o; o >>= 1) ss += __shfl_xor(ss, o);
    float n  = fmaxf(sqrtf(ss), EPSF);
    float sc = tanhf(n) / n;                    // expmap0 scale
    out[(size_t)d*64 + lane] = a * sc;
  }
}

extern "C" void kernel_launch(void* const* d_in, const int* in_sizes, int n_in,
                              void* d_out, int out_size, void* d_ws, size_t ws_size,
                              hipStream_t stream) {
  const float* x      = (const float*)d_in[0];
  const float* W1     = (const float*)d_in[1];
  const float* a_src1 = (const float*)d_in[2];
  const float* a_dst1 = (const float*)d_in[3];
  const float* W2     = (const float*)d_in[4];
  const float* a_src2 = (const float*)d_in[5];
  const float* a_dst2 = (const float*)d_in[6];
  const int*   ei0    = (const int*)d_in[7];
  const int*   ei1    = (const int*)d_in[8];
  const int N  = in_sizes[0] / 128;
  const int E0 = in_sizes[7] / 2;
  const int E1 = in_sizes[8] / 2;
  const int* src0 = ei0;  const int* dst0 = ei0 + E0;
  const int* src1 = ei1;  const int* dst1 = ei1 + E1;
  float* out = (float*)d_out;
  const int nb = (N + 127) >> 7;

  float* ws = (float*)d_ws;
  size_t o = 0;
  float* es1   = ws + o; o += (size_t)N*4;
  float* ed1   = ws + o; o += (size_t)N*4;
  float* es2   = ws + o; o += (size_t)N;
  float* ed2   = ws + o; o += (size_t)N;
  float* denom1= ws + o; o += (size_t)N*4;
  _Float16* h1h = (_Float16*)(ws + o); o += (size_t)N*128;  // N*256 halves
  _Float16* t2h = (_Float16*)(ws + o); o += (size_t)N*128;  // N*256 halves
  _Float16* h2h = (_Float16*)(ws + o); o += (size_t)N*32;   // N*64 halves
  o += (o & 1);                                             // 8B align
  half4* w0    = (half4*)(ws + o); o += (size_t)E0*2;       // E0*4 halves
  u64* temp0 = (u64*)(ws + o); o += (size_t)E0*2;
  u64* temp1 = (u64*)(ws + o); o += (size_t)E1*2;
  int* iws = (int*)(ws + o);
  size_t io = 0;
  int* rowptr0 = iws + io; io += N + 1;
  int* rowptr1 = iws + io; io += N + 1;
  int* bcnt0   = iws + io; io += NBMAX;  // bcnt0/bcnt1 adjacent: one memset
  int* bcnt1   = iws + io; io += NBMAX;
  int* bbase0  = iws + io; io += NBMAX + 1;
  int* bbase1  = iws + io; io += NBMAX + 1;
  int* bcur0   = iws + io; io += NBMAX;
  int* bcur1   = iws + io; io += NBMAX;
  int* csrc0   = iws + io; io += E0;
  int* csrc1   = iws + io; io += E1;

  dim3 blk(256);
  const int blocksA0 = (E0 + 4095) / 4096;
  const int blocksA1 = (E1 + 4095) / 4096;
  hipMemsetAsync(bcnt0, 0, 2*NBMAX*sizeof(int), stream);
  // layer-1 GEMM first: bucketB2 consumes es1/ed1
  k_gemm1  <<<(N+31)/32, blk, 0, stream>>>(x, W1, a_src1, a_dst1, h1h, es1, ed1, N);
  // CSR build (+ graph-0 edge weights & denominators fused into bucketB2)
  k_bhist  <<<1024, blk, 0, stream>>>(dst0, E0, dst1, E1, bcnt0, bcnt1, nb);
  k_bscan  <<<1, 1024, 0, stream>>>(bcnt0, bbase0, bcur0, bcnt1, bbase1, bcur1, nb);
  k_bucketA<<<blocksA0 + blocksA1, blk, 0, stream>>>(
      src0, dst0, bcur0, temp0, E0, blocksA0, src1, dst1, bcur1, temp1, E1, nb);
  k_bucketB2<<<2*nb, blk, 0, stream>>>(temp0, bbase0, rowptr0, csrc0,
                                       es1, ed1, w0, denom1,
                                       temp1, bbase1, rowptr1, csrc1, N, nb);
  // layer-1 aggregation (pure gather) + fused maps -> t2h
  k_agg1_csr<<<2048, blk, 0, stream>>>(rowptr0, csrc0, w0, denom1, h1h, t2h, N);
  // layer 2
  k_gemm2  <<<(N+31)/32, blk, 0, stream>>>(t2h, W2, a_src2, a_dst2, h2h, es2, ed2, N);
  k_agg2_csr<<<2048, blk, 0, stream>>>(rowptr1, csrc1, es2, ed2, h2h, out, N);
}

// Round 18
// 307.012 us; speedup vs baseline: 1.4990x; 1.1019x over previous
//
#include <hip/hip_runtime.h>

#define EPSF 1e-7f
#define NBMAX 512   // max dst-buckets (ceil(N/128)); N=50000 -> 391

typedef __attribute__((ext_vector_type(4))) _Float16 half4;
typedef unsigned long long u64;

__device__ __forceinline__ float lrelu02(float x){ return x > 0.f ? x : 0.2f*x; }

// ---------------- CSR build (bucket-local, no N-sized scan) ----------------
__global__ __launch_bounds__(256) void k_bhist(
    const int* __restrict__ dst0, int E0, const int* __restrict__ dst1, int E1,
    int* __restrict__ bcnt0, int* __restrict__ bcnt1, int nb) {
  __shared__ int h0[NBMAX], h1[NBMAX];
  const int tid = threadIdx.x;
  const int g = blockIdx.x*blockDim.x + tid;
  const int stride = gridDim.x*blockDim.x;
  for (int i = tid; i < nb; i += 256) { h0[i] = 0; h1[i] = 0; }
  __syncthreads();
  for (int i = g; i < E0; i += stride) atomicAdd(&h0[dst0[i] >> 7], 1);
  for (int i = g; i < E1; i += stride) atomicAdd(&h1[dst1[i] >> 7], 1);
  __syncthreads();
  for (int i = tid; i < nb; i += 256) {
    if (h0[i]) atomicAdd(&bcnt0[i], h0[i]);
    if (h1[i]) atomicAdd(&bcnt1[i], h1[i]);
  }
}

__global__ __launch_bounds__(1024) void k_bscan(
    const int* __restrict__ bcnt0, int* __restrict__ bbase0, int* __restrict__ bcur0,
    const int* __restrict__ bcnt1, int* __restrict__ bbase1, int* __restrict__ bcur1,
    int nb) {
  __shared__ int wt[16];
  const int tid = threadIdx.x;
  const int half = tid >> 9, idx = tid & 511;
  const int* bcnt = half ? bcnt1 : bcnt0;
  int* bbase = half ? bbase1 : bbase0;
  int* bcur  = half ? bcur1  : bcur0;
  int v = (idx < nb) ? bcnt[idx] : 0;
  const int lane = tid & 63, w = tid >> 6;
  int inc = v;
  #pragma unroll
  for (int o = 1; o < 64; o <<= 1) { int t = __shfl_up(inc, o); if (lane >= o) inc += t; }
  if (lane == 63) wt[w] = inc;
  __syncthreads();
  int woff = 0;
  for (int i = half*8; i < w; ++i) woff += wt[i];
  int excl = woff + inc - v;
  if (idx < nb) { bbase[idx] = excl; bcur[idx] = excl; }
  if (idx == nb-1) bbase[nb] = excl + v;
}

__global__ __launch_bounds__(256) void k_bucketA(
    const int* __restrict__ src0, const int* __restrict__ dst0,
    int* __restrict__ bcur0, u64* __restrict__ temp0, int E0, int blocksA0,
    const int* __restrict__ src1, const int* __restrict__ dst1,
    int* __restrict__ bcur1, u64* __restrict__ temp1, int E1, int nb) {
  const int g0 = (blockIdx.x < blocksA0);
  const int* src = g0 ? src0 : src1;
  const int* dst = g0 ? dst0 : dst1;
  int* bcur      = g0 ? bcur0 : bcur1;
  u64* temp      = g0 ? temp0 : temp1;
  const int E    = g0 ? E0 : E1;
  const int cb   = g0 ? blockIdx.x : blockIdx.x - blocksA0;
  __shared__ int hist[NBMAX];
  __shared__ int lbase[NBMAX];
  const int tid = threadIdx.x;
  const int chunk0 = cb * 4096;
  const int e_end = min(chunk0 + 4096, E);
  for (int i = tid; i < nb; i += 256) hist[i] = 0;
  __syncthreads();
  for (int i = chunk0 + tid; i < e_end; i += 256)
    atomicAdd(&hist[dst[i] >> 7], 1);
  __syncthreads();
  for (int bn = tid; bn < nb; bn += 256) {
    int c = hist[bn];
    lbase[bn] = c ? atomicAdd(&bcur[bn], c) : 0;
    hist[bn] = 0;
  }
  __syncthreads();
  for (int i = chunk0 + tid; i < e_end; i += 256) {
    int d = dst[i];
    int bn = d >> 7;
    int off = atomicAdd(&hist[bn], 1);
    temp[(size_t)lbase[bn] + off] = ((u64)(unsigned)d << 32) | (unsigned)src[i];
  }
}

// pass B: per bucket, per-dst count + local scan -> rowptr; scatter csrc.
// For graph 0 additionally: per-edge attention weights (fp16).
__global__ __launch_bounds__(256) void k_bucketB2(
    const u64* __restrict__ temp0, const int* __restrict__ bbase0,
    int* __restrict__ rowptr0, int* __restrict__ csrc0,
    const float* __restrict__ es1, const float* __restrict__ ed1,
    half4* __restrict__ w0,
    const u64* __restrict__ temp1, const int* __restrict__ bbase1,
    int* __restrict__ rowptr1, int* __restrict__ csrc1, int N, int nb) {
  const int g0 = (blockIdx.x < nb);
  const u64* temp = g0 ? temp0 : temp1;
  const int* bbase = g0 ? bbase0 : bbase1;
  int* rowptr = g0 ? rowptr0 : rowptr1;
  int* csrc   = g0 ? csrc0 : csrc1;
  const int b = g0 ? blockIdx.x : blockIdx.x - nb;
  __shared__ int lcnt[128];
  __shared__ int lcur[128];
  __shared__ int wt4[4];
  __shared__ float ledv[512];
  const int tid = threadIdx.x;
  const int d0 = b << 7;
  const int d1 = min(d0 + 128, N);
  const int lo = bbase[b], hi = bbase[b+1];
  if (tid < 128) lcnt[tid] = 0;
  if (g0) {
    for (int i = tid; i < (d1 - d0)*4; i += 256) ledv[i] = ed1[d0*4 + i];
  }
  __syncthreads();
  for (int k = lo + tid; k < hi; k += 256)
    atomicAdd(&lcnt[(int)(temp[k] >> 32) - d0], 1);
  __syncthreads();
  int v = (tid < 128) ? lcnt[tid] : 0;
  const int lane = tid & 63, w = tid >> 6;
  int inc = v;
  #pragma unroll
  for (int o = 1; o < 64; o <<= 1) { int t = __shfl_up(inc, o); if (lane >= o) inc += t; }
  if (lane == 63) wt4[w] = inc;
  __syncthreads();
  int woff = 0;
  for (int i = 0; i < w; ++i) woff += wt4[i];
  int excl = lo + woff + inc - v;
  if (tid < d1 - d0) { rowptr[d0 + tid] = excl; lcur[tid] = excl; }
  if (b == nb-1 && tid == 0) rowptr[N] = hi;
  __syncthreads();
  for (int k = lo + tid; k < hi; k += 256) {
    u64 p = temp[k];
    int d = (int)(p >> 32);
    int s = (int)(unsigned)p;
    int pos = atomicAdd(&lcur[d - d0], 1);
    csrc[pos] = s;
    if (g0) {
      float4 e = *(const float4*)(es1 + (size_t)s*4);
      int ld = (d - d0)*4;
      half4 wh;
      wh.x = (_Float16)__expf(lrelu02(e.x + ledv[ld+0]));
      wh.y = (_Float16)__expf(lrelu02(e.y + ledv[ld+1]));
      wh.z = (_Float16)__expf(lrelu02(e.z + ledv[ld+2]));
      wh.w = (_Float16)__expf(lrelu02(e.w + ledv[ld+3]));
      w0[pos] = wh;
    }
  }
}

// ------------- layer1: logmap0(x) @ W1 -> h1 (fp16) [N,256]; es1/ed1 [N,4]
//   j-blocked: lane owns cols j=lane*4..lane*4+3; wave owns 8 rows; block = 32 rows
__global__ __launch_bounds__(256) void k_gemm1(
    const float* __restrict__ x, const float* __restrict__ W1,
    const float* __restrict__ a_src, const float* __restrict__ a_dst,
    _Float16* __restrict__ h1h, float* __restrict__ es, float* __restrict__ ed, int N) {
  __shared__ float t[32][128];          // 16 KB
  const int tid = threadIdx.x;
  const int block0 = blockIdx.x * 32;
  #pragma unroll
  for (int p = 0; p < 4; ++p) {
    const int r = (tid >> 5) + p*8, c = (tid & 31) * 4;
    const int row = block0 + r;
    float4 v = make_float4(0.f,0.f,0.f,0.f);
    if (row < N) v = *(const float4*)(x + (size_t)row*128 + c);
    float ss = v.x*v.x + v.y*v.y + v.z*v.z + v.w*v.w;
    #pragma unroll
    for (int o = 16; o; o >>= 1) ss += __shfl_xor(ss, o);
    float n  = fmaxf(sqrtf(ss), EPSF);
    float nc = fminf(n, 1.f - 1e-5f);
    float sc = atanhf(nc) / n;                 // logmap0 scale
    *(float4*)&t[r][c] = make_float4(v.x*sc, v.y*sc, v.z*sc, v.w*sc);
  }
  __syncthreads();

  const int wv = tid >> 6, lane = tid & 63;
  const int j = lane * 4;               // columns j..j+3
  const int r0 = wv * 8;                // wave's 8 rows
  float4 acc[8];
  #pragma unroll
  for (int r = 0; r < 8; ++r) acc[r] = make_float4(0.f,0.f,0.f,0.f);
  for (int k = 0; k < 128; k += 4) {
    float4 w0 = *(const float4*)(W1 + (size_t)(k+0)*256 + j);
    float4 w1 = *(const float4*)(W1 + (size_t)(k+1)*256 + j);
    float4 w2 = *(const float4*)(W1 + (size_t)(k+2)*256 + j);
    float4 w3 = *(const float4*)(W1 + (size_t)(k+3)*256 + j);
    #pragma unroll
    for (int r = 0; r < 8; ++r) {
      float4 tv = *(const float4*)&t[r0 + r][k];   // wave-uniform addr: broadcast
      acc[r].x += tv.x*w0.x + tv.y*w1.x + tv.z*w2.x + tv.w*w3.x;
      acc[r].y += tv.x*w0.y + tv.y*w1.y + tv.z*w2.y + tv.w*w3.y;
      acc[r].z += tv.x*w0.z + tv.y*w1.z + tv.z*w2.z + tv.w*w3.z;
      acc[r].w += tv.x*w0.w + tv.y*w1.w + tv.z*w2.w + tv.w*w3.w;
    }
  }
  const int head = lane >> 4;
  const float4 as4 = *(const float4*)(a_src + j);   // j = head*64 + (lane&15)*4
  const float4 ad4 = *(const float4*)(a_dst + j);
  #pragma unroll
  for (int r = 0; r < 8; ++r) {
    int row = block0 + r0 + r;
    if (row >= N) break;
    float4 a = acc[r];
    half4 hv; hv.x = (_Float16)a.x; hv.y = (_Float16)a.y;
              hv.z = (_Float16)a.z; hv.w = (_Float16)a.w;
    *(half4*)(h1h + (size_t)row*256 + j) = hv;
    float ps = a.x*as4.x + a.y*as4.y + a.z*as4.z + a.w*as4.w;
    float pd = a.x*ad4.x + a.y*ad4.y + a.z*ad4.z + a.w*ad4.w;
    #pragma unroll
    for (int o = 8; o; o >>= 1) { ps += __shfl_xor(ps, o); pd += __shfl_xor(pd, o); }
    if ((lane & 15) == 0) { es[row*4 + head] = ps; ed[row*4 + head] = pd; }
  }
}

// ------------- layer1 aggregation: software-pipelined gather+FMA
//   wave per dst; lane owns cols lane*4..+3 (head = lane>>4); in-register wsum
__global__ void k_agg1_csr(const int* __restrict__ rowptr, const int* __restrict__ csrc,
                           const half4* __restrict__ w0,
                           const _Float16* __restrict__ h1h, _Float16* __restrict__ t2h,
                           int N) {
  int tidg = blockIdx.x*blockDim.x + threadIdx.x;
  int wid = tidg >> 6, lane = tidg & 63;
  int nw = (gridDim.x * blockDim.x) >> 6;
  const int h = lane >> 4;
  const _Float16* wp = (const _Float16*)w0;
  for (int d = wid; d < N; d += nw) {
    const int beg = rowptr[d], end = rowptr[d+1];
    float4 acc = make_float4(0.f,0.f,0.f,0.f);
    float wsum = 0.f;
    int k = beg;
    const int kend4 = beg + ((end - beg) & ~3);
    if (k < kend4) {
      int s0 = csrc[k], s1 = csrc[k+1], s2 = csrc[k+2], s3 = csrc[k+3];
      float wa = (float)wp[(size_t)(k+0)*4 + h];
      float wb = (float)wp[(size_t)(k+1)*4 + h];
      float wc = (float)wp[(size_t)(k+2)*4 + h];
      float wd = (float)wp[(size_t)(k+3)*4 + h];
      for (;;) {
        // issue current gathers immediately (addresses already known)
        half4 v0 = *(const half4*)(h1h + (size_t)s0*256 + lane*4);
        half4 v1 = *(const half4*)(h1h + (size_t)s1*256 + lane*4);
        half4 v2 = *(const half4*)(h1h + (size_t)s2*256 + lane*4);
        half4 v3 = *(const half4*)(h1h + (size_t)s3*256 + lane*4);
        k += 4;
        const bool more = (k < kend4);
        int t0 = 0, t1 = 0, t2 = 0, t3 = 0;
        float ua = 0.f, ub = 0.f, uc = 0.f, ud = 0.f;
        if (more) {                      // prefetch next indices + weights
          t0 = csrc[k]; t1 = csrc[k+1]; t2 = csrc[k+2]; t3 = csrc[k+3];
          ua = (float)wp[(size_t)(k+0)*4 + h];
          ub = (float)wp[(size_t)(k+1)*4 + h];
          uc = (float)wp[(size_t)(k+2)*4 + h];
          ud = (float)wp[(size_t)(k+3)*4 + h];
        }
        wsum += (wa + wb) + (wc + wd);
        acc.x += wa*(float)v0.x + wb*(float)v1.x + wc*(float)v2.x + wd*(float)v3.x;
        acc.y += wa*(float)v0.y + wb*(float)v1.y + wc*(float)v2.y + wd*(float)v3.y;
        acc.z += wa*(float)v0.z + wb*(float)v1.z + wc*(float)v2.z + wd*(float)v3.z;
        acc.w += wa*(float)v0.w + wb*(float)v1.w + wc*(float)v2.w + wd*(float)v3.w;
        if (!more) break;
        s0 = t0; s1 = t1; s2 = t2; s3 = t3;
        wa = ua; wb = ub; wc = uc; wd = ud;
      }
    }
    for (; k < end; ++k) {
      int s = csrc[k];
      float wa = (float)wp[(size_t)k*4 + h];
      half4 hv = *(const half4*)(h1h + (size_t)s*256 + lane*4);
      wsum += wa;
      acc.x += wa*(float)hv.x; acc.y += wa*(float)hv.y;
      acc.z += wa*(float)hv.z; acc.w += wa*(float)hv.w;
    }
    float inv = 1.f / (wsum + 1e-16f);
    float ax = acc.x*inv, ay = acc.y*inv, az = acc.z*inv, aw = acc.w*inv;
    // fused t2 = logmap0(expmap0(agg)) over the 256-dim row
    float ss = ax*ax + ay*ay + az*az + aw*aw;
    #pragma unroll
    for (int o = 32; o; o >>= 1) ss += __shfl_xor(ss, o);
    float n  = fmaxf(sqrtf(ss), EPSF);
    float s1 = tanhf(n) / n;                    // expmap0 scale
    float n2 = fmaxf(s1 * n, EPSF);             // = tanh(n), clamped
    float nc = fminf(n2, 1.f - 1e-5f);
    float sc = s1 * atanhf(nc) / n2;
    half4 o4; o4.x = (_Float16)(ax*sc); o4.y = (_Float16)(ay*sc);
              o4.z = (_Float16)(az*sc); o4.w = (_Float16)(aw*sc);
    *(half4*)(t2h + (size_t)d*256 + lane*4) = o4;
  }
}

// ------------- layer2: t2h (fp16) [N,256] @ W2 [256,64] -> h2 (fp16); es2/ed2 [N]
//   block = 32 rows; wave owns 8 rows (rg-pairs); lane owns cols jj=(lane&15)*4
#define T2PAD 260
__global__ __launch_bounds__(256) void k_gemm2(
    const _Float16* __restrict__ t2h, const float* __restrict__ W2,
    const float* __restrict__ a_src, const float* __restrict__ a_dst,
    _Float16* __restrict__ h2h, float* __restrict__ es, float* __restrict__ ed, int N) {
  __shared__ float tile[32*T2PAD];              // ~33 KB, padded rows (bank spread)
  const int tid = threadIdx.x;
  const int block0 = blockIdx.x * 32;
  int validq = (block0 < N ? ((N - block0 < 32) ? (N - block0) : 32) : 0) * 64;
  const half4* srcp = (const half4*)(t2h + (size_t)block0 * 256);
  #pragma unroll
  for (int i0 = 0; i0 < 2048; i0 += 256) {
    int i = i0 + tid;
    half4 v; v.x = v.y = v.z = v.w = (_Float16)0.f;
    if (i < validq) v = srcp[i];
    int r = i >> 6, c = (i & 63) * 4;
    *(float4*)&tile[r*T2PAD + c] =
        make_float4((float)v.x, (float)v.y, (float)v.z, (float)v.w);
  }
  __syncthreads();
  const int wv = tid >> 6, lane = tid & 63;
  const int jj = (lane & 15) * 4;               // columns jj..jj+3
  const int rg = lane >> 4;                     // rowgroup 0..3
  const int rbase = wv*8 + rg*2;                // wave's rows: rbase, rbase+1
  float4 acc[2];
  acc[0] = make_float4(0.f,0.f,0.f,0.f);
  acc[1] = make_float4(0.f,0.f,0.f,0.f);
  for (int k = 0; k < 256; k += 4) {
    float4 w0 = *(const float4*)(W2 + (size_t)(k+0)*64 + jj);
    float4 w1 = *(const float4*)(W2 + (size_t)(k+1)*64 + jj);
    float4 w2 = *(const float4*)(W2 + (size_t)(k+2)*64 + jj);
    float4 w3 = *(const float4*)(W2 + (size_t)(k+3)*64 + jj);
    #pragma unroll
    for (int rr = 0; rr < 2; ++rr) {
      float4 tv = *(const float4*)&tile[(rbase + rr)*T2PAD + k]; // 16-lane broadcast
      acc[rr].x += tv.x*w0.x + tv.y*w1.x + tv.z*w2.x + tv.w*w3.x;
      acc[rr].y += tv.x*w0.y + tv.y*w1.y + tv.z*w2.y + tv.w*w3.y;
      acc[rr].z += tv.x*w0.z + tv.y*w1.z + tv.z*w2.z + tv.w*w3.z;
      acc[rr].w += tv.x*w0.w + tv.y*w1.w + tv.z*w2.w + tv.w*w3.w;
    }
  }
  const float4 as4 = *(const float4*)(a_src + jj);
  const float4 ad4 = *(const float4*)(a_dst + jj);
  #pragma unroll
  for (int rr = 0; rr < 2; ++rr) {
    int row = block0 + rbase + rr;
    if (row < N) {
      float4 a = acc[rr];
      half4 hv; hv.x = (_Float16)a.x; hv.y = (_Float16)a.y;
                hv.z = (_Float16)a.z; hv.w = (_Float16)a.w;
      *(half4*)(h2h + (size_t)row*64 + jj) = hv;
      float ps = a.x*as4.x + a.y*as4.y + a.z*as4.z + a.w*as4.w;
      float pd = a.x*ad4.x + a.y*ad4.y + a.z*ad4.z + a.w*ad4.w;
      #pragma unroll
      for (int o = 8; o; o >>= 1) { ps += __shfl_xor(ps, o); pd += __shfl_xor(pd, o); }
      if ((lane & 15) == 0) { es[row] = ps; ed[row] = pd; }
    }
  }
}

// ------------- layer2 aggregation (CSR, wave per dst, pipelined) + fused expmap0 ---------
__global__ void k_agg2_csr(const int* __restrict__ rowptr, const int* __restrict__ csrc,
                           const float* __restrict__ es, const float* __restrict__ ed,
                           const _Float16* __restrict__ h2h, float* __restrict__ out, int N) {
  int tidg = blockIdx.x*blockDim.x + threadIdx.x;
  int wid = tidg >> 6, lane = tidg & 63;
  int nw = (gridDim.x * blockDim.x) >> 6;
  for (int d = wid; d < N; d += nw) {
    const int beg = rowptr[d], end = rowptr[d+1];
    const float edv = ed[d];
    float acc = 0.f, wsum = 0.f;
    int k = beg;
    const int kend4 = beg + ((end - beg) & ~3);
    if (k < kend4) {
      int s0 = csrc[k], s1 = csrc[k+1], s2 = csrc[k+2], s3 = csrc[k+3];
      for (;;) {
        float e0 = es[s0], e1 = es[s1], e2 = es[s2], e3 = es[s3];
        float x0 = (float)h2h[(size_t)s0*64 + lane];
        float x1 = (float)h2h[(size_t)s1*64 + lane];
        float x2 = (float)h2h[(size_t)s2*64 + lane];
        float x3 = (float)h2h[(size_t)s3*64 + lane];
        k += 4;
        const bool more = (k < kend4);
        int t0 = 0, t1 = 0, t2 = 0, t3 = 0;
        if (more) { t0 = csrc[k]; t1 = csrc[k+1]; t2 = csrc[k+2]; t3 = csrc[k+3]; }
        float w0 = __expf(lrelu02(e0 + edv));
        float w1 = __expf(lrelu02(e1 + edv));
        float w2 = __expf(lrelu02(e2 + edv));
        float w3 = __expf(lrelu02(e3 + edv));
        wsum += (w0 + w1) + (w2 + w3);
        acc += w0*x0 + w1*x1 + w2*x2 + w3*x3;
        if (!more) break;
        s0 = t0; s1 = t1; s2 = t2; s3 = t3;
      }
    }
    for (; k < end; ++k) {
      int s = csrc[k];
      float w = __expf(lrelu02(es[s] + edv));
      wsum += w;
      acc += w * (float)h2h[(size_t)s*64 + lane];
    }
    float a = acc / (wsum + 1e-16f);
    float ss = a*a;
    #pragma unroll
    for (int o = 32; o; o >>= 1) ss += __shfl_xor(ss, o);
    float n  = fmaxf(sqrtf(ss), EPSF);
    float sc = tanhf(n) / n;                    // expmap0 scale
    out[(size_t)d*64 + lane] = a * sc;
  }
}

extern "C" void kernel_launch(void* const* d_in, const int* in_sizes, int n_in,
                              void* d_out, int out_size, void* d_ws, size_t ws_size,
                              hipStream_t stream) {
  const float* x      = (const float*)d_in[0];
  const float* W1     = (const float*)d_in[1];
  const float* a_src1 = (const float*)d_in[2];
  const float* a_dst1 = (const float*)d_in[3];
  const float* W2     = (const float*)d_in[4];
  const float* a_src2 = (const float*)d_in[5];
  const float* a_dst2 = (const float*)d_in[6];
  const int*   ei0    = (const int*)d_in[7];
  const int*   ei1    = (const int*)d_in[8];
  const int N  = in_sizes[0] / 128;
  const int E0 = in_sizes[7] / 2;
  const int E1 = in_sizes[8] / 2;
  const int* src0 = ei0;  const int* dst0 = ei0 + E0;
  const int* src1 = ei1;  const int* dst1 = ei1 + E1;
  float* out = (float*)d_out;
  const int nb = (N + 127) >> 7;

  float* ws = (float*)d_ws;
  size_t o = 0;
  float* es1   = ws + o; o += (size_t)N*4;
  float* ed1   = ws + o; o += (size_t)N*4;
  float* es2   = ws + o; o += (size_t)N;
  float* ed2   = ws + o; o += (size_t)N;
  _Float16* h1h = (_Float16*)(ws + o); o += (size_t)N*128;  // N*256 halves
  _Float16* t2h = (_Float16*)(ws + o); o += (size_t)N*128;  // N*256 halves
  _Float16* h2h = (_Float16*)(ws + o); o += (size_t)N*32;   // N*64 halves
  o += (o & 1);                                             // 8B align
  half4* w0    = (half4*)(ws + o); o += (size_t)E0*2;       // E0*4 halves
  u64* temp0 = (u64*)(ws + o); o += (size_t)E0*2;
  u64* temp1 = (u64*)(ws + o); o += (size_t)E1*2;
  int* iws = (int*)(ws + o);
  size_t io = 0;
  int* rowptr0 = iws + io; io += N + 1;
  int* rowptr1 = iws + io; io += N + 1;
  int* bcnt0   = iws + io; io += NBMAX;  // bcnt0/bcnt1 adjacent: one memset
  int* bcnt1   = iws + io; io += NBMAX;
  int* bbase0  = iws + io; io += NBMAX + 1;
  int* bbase1  = iws + io; io += NBMAX + 1;
  int* bcur0   = iws + io; io += NBMAX;
  int* bcur1   = iws + io; io += NBMAX;
  int* csrc0   = iws + io; io += E0;
  int* csrc1   = iws + io; io += E1;

  dim3 blk(256);
  const int blocksA0 = (E0 + 4095) / 4096;
  const int blocksA1 = (E1 + 4095) / 4096;
  hipMemsetAsync(bcnt0, 0, 2*NBMAX*sizeof(int), stream);
  // layer-1 GEMM first: bucketB2 consumes es1/ed1
  k_gemm1  <<<(N+31)/32, blk, 0, stream>>>(x, W1, a_src1, a_dst1, h1h, es1, ed1, N);
  // CSR build (+ graph-0 edge weights fused into bucketB2)
  k_bhist  <<<1024, blk, 0, stream>>>(dst0, E0, dst1, E1, bcnt0, bcnt1, nb);
  k_bscan  <<<1, 1024, 0, stream>>>(bcnt0, bbase0, bcur0, bcnt1, bbase1, bcur1, nb);
  k_bucketA<<<blocksA0 + blocksA1, blk, 0, stream>>>(
      src0, dst0, bcur0, temp0, E0, blocksA0, src1, dst1, bcur1, temp1, E1, nb);
  k_bucketB2<<<2*nb, blk, 0, stream>>>(temp0, bbase0, rowptr0, csrc0,
                                       es1, ed1, w0,
                                       temp1, bbase1, rowptr1, csrc1, N, nb);
  // layer-1 aggregation (pipelined gather) + fused maps -> t2h
  k_agg1_csr<<<2048, blk, 0, stream>>>(rowptr0, csrc0, w0, h1h, t2h, N);
  // layer 2
  k_gemm2  <<<(N+31)/32, blk, 0, stream>>>(t2h, W2, a_src2, a_dst2, h2h, es2, ed2, N);
  k_agg2_csr<<<2048, blk, 0, stream>>>(rowptr1, csrc1, es2, ed2, h2h, out, N);
}